// Round 1
// baseline (396.117 us; speedup 1.0000x reference)
//
#include <hip/hip_runtime.h>
#include <math.h>

// PCEN: per-(b,k) IIR smoother over T + pointwise pow compression.
// x: [B=32, C=1, K=128, T=8000] fp32. One block per sequence (4096 blocks).
// R4: 512-thread blocks (CHUNK=16) -> 4 blocks/CU for load/compute phase
// staggering (R3's 1024-thread blocks gave only 2/CU and serialized HBM vs
// VALU phases: 50% + 50%). Scan runs in g-space (g = f/s) so the recurrence
// is a single fmaf and eps+f fuses as fmaf(s,g,eps). All pointwise pow math
// uses raw v_exp_f32/v_log_f32 builtins (no OCML wrappers). Output stored
// nontemporally so streaming writes don't evict x from L3.

constexpr int   T_LEN = 8000;
constexpr int   CHUNK = 16;
constexpr int   NTH   = 512;
constexpr int   NWAVE = NTH / 64;            // 8
constexpr int   NACT  = T_LEN / CHUNK;       // 500 active threads
constexpr int   KDIM  = 128;
constexpr float EPS_F = 1e-6f;
constexpr float LOG2E = 1.4426950408889634f;

typedef float f32x4 __attribute__((ext_vector_type(4)));

__global__ __launch_bounds__(NTH, 8) void pcen_kernel(
    const float* __restrict__ x,
    const float* __restrict__ log_s,
    const float* __restrict__ log_alpha,
    const float* __restrict__ log_delta,
    const float* __restrict__ log_r,
    float* __restrict__ out)
{
    __shared__ float wAs[NWAVE], wBs[NWAVE];

    const int seq  = blockIdx.x;              // seq = b*K + k  (C == 1)
    const int k    = seq & (KDIM - 1);
    const int tid  = threadIdx.x;
    const int lane = tid & 63;
    const int wave = tid >> 6;

    // Per-k parameters (uniform across the block). exp via hw v_exp_f32.
    const float ls      = log_s[k];
    const float e_ns    = __builtin_amdgcn_exp2f(-ls * LOG2E);   // e^{-ls}
    const float inv_s   = 1.0f + e_ns;                           // 1/s
    const float s       = 1.0f / inv_s;                          // sigmoid(ls)
    const float a       = e_ns * s;                              // 1 - s
    const float alpha   = __builtin_amdgcn_exp2f(log_alpha[k] * LOG2E);
    const float delta   = __builtin_amdgcn_exp2f(log_delta[k] * LOG2E);
    const float r       = __builtin_amdgcn_exp2f(log_r[k] * LOG2E);
    const float delta_r = __builtin_amdgcn_exp2f(r * log_delta[k] * LOG2E); // delta^r

    const float* xp = x   + (size_t)seq * T_LEN + tid * CHUNK;
    float*       op = out + (size_t)seq * T_LEN + tid * CHUNK;
    const bool active = tid < NACT;

    // ---- load 16 contiguous floats (four float4s), register-resident ----
    float xv[CHUNK];
    if (active) {
        #pragma unroll
        for (int v = 0; v < CHUNK / 4; ++v) {
            f32x4 t = ((const f32x4*)xp)[v];
            xv[4*v+0] = t[0]; xv[4*v+1] = t[1];
            xv[4*v+2] = t[2]; xv[4*v+3] = t[3];
        }
    }

    // ---- carry pass in g-space (g = f/s): g_t = a*g_{t-1} + x_t ----
    // Local zero-init prefixes q_j kept in regs; thread 0 is the absolute
    // start (A = 0 map kills any f_init dependence downstream).
    float q[CHUNK];
    float A = 1.0f, B = 0.0f;                 // identity for inactive tail
    if (active) {
        float g;
        if (tid == 0) {
            g = xv[0] * inv_s; q[0] = g;      // f[0] = x[0]  ->  g[0] = x[0]/s
            #pragma unroll
            for (int j = 1; j < CHUNK; ++j) { g = fmaf(a, g, xv[j]); q[j] = g; }
            A = 0.0f;
        } else {
            g = 0.0f;
            #pragma unroll
            for (int j = 0; j < CHUNK; ++j) { g = fmaf(a, g, xv[j]); q[j] = g; }
            const float a2 = a * a, a4 = a2 * a2, a8 = a4 * a4;
            A = a8 * a8;                      // a^16
        }
        B = g;
    }

    // ---- intra-wave inclusive scan (64 lanes), compose current∘previous ----
    #pragma unroll
    for (int off = 1; off < 64; off <<= 1) {
        const float pA = __shfl_up(A, off, 64);
        const float pB = __shfl_up(B, off, 64);
        if (lane >= off) {
            B = fmaf(A, pB, B);
            A = A * pA;
        }
    }

    // ---- cross-wave: wave 0 scans the 8 wave carries, writes EXCLUSIVE prefixes ----
    if (lane == 63) { wAs[wave] = A; wBs[wave] = B; }
    __syncthreads();
    if (wave == 0) {
        float cA = (lane < NWAVE) ? wAs[lane] : 1.0f;
        float cB = (lane < NWAVE) ? wBs[lane] : 0.0f;
        #pragma unroll
        for (int off = 1; off < NWAVE; off <<= 1) {
            const float pA = __shfl_up(cA, off, 64);
            const float pB = __shfl_up(cB, off, 64);
            if (lane >= off) {
                cB = fmaf(cA, pB, cB);
                cA = cA * pA;
            }
        }
        if (lane < NWAVE - 1) { wAs[lane + 1] = cA; wBs[lane + 1] = cB; }
        if (lane == 0)        { wAs[0] = 1.0f;      wBs[0] = 0.0f;      }
    }
    __syncthreads();

    // incoming g value for this thread (wave-prefix maps have A=0 past
    // thread 0, so entering value is just the composed B).
    float eA = __shfl_up(A, 1, 64);
    float eB = __shfl_up(B, 1, 64);
    if (lane == 0) { eA = 1.0f; eB = 0.0f; }
    float fin = fmaf(eA, wBs[wave], eB);
    if (tid == 0) fin = 0.0f;                 // thread 0 uses q_j directly

    // ---- apply: g_j = a^(j+1)*fin + q_j ; f = s*g ; PCEN pointwise; store ----
    if (active) {
        float pw = a;
        #pragma unroll
        for (int j = 0; j < CHUNK; ++j) {
            const float g   = fmaf(pw, fin, q[j]);
            pw *= a;
            const float lg  = __builtin_amdgcn_logf(fmaf(s, g, EPS_F));  // log2(eps+f)
            const float inv = __builtin_amdgcn_exp2f(-alpha * lg);       // (eps+f)^(-alpha)
            const float u   = fmaf(xv[j], inv, delta);
            xv[j] = __builtin_amdgcn_exp2f(r * __builtin_amdgcn_logf(u)) - delta_r;
        }
        #pragma unroll
        for (int v = 0; v < CHUNK / 4; ++v) {
            f32x4 t;
            t[0] = xv[4*v+0]; t[1] = xv[4*v+1];
            t[2] = xv[4*v+2]; t[3] = xv[4*v+3];
            __builtin_nontemporal_store(t, ((f32x4*)op) + v);
        }
    }
}

extern "C" void kernel_launch(void* const* d_in, const int* in_sizes, int n_in,
                              void* d_out, int out_size, void* d_ws, size_t ws_size,
                              hipStream_t stream) {
    const float* x         = (const float*)d_in[0];
    const float* log_s     = (const float*)d_in[1];
    const float* log_alpha = (const float*)d_in[2];
    const float* log_delta = (const float*)d_in[3];
    const float* log_r     = (const float*)d_in[4];
    float* out = (float*)d_out;

    const int nseq = in_sizes[0] / T_LEN;   // 32*1*128 = 4096 sequences
    pcen_kernel<<<nseq, NTH, 0, stream>>>(x, log_s, log_alpha, log_delta, log_r, out);
}

// Round 2
// 240.728 us; speedup vs baseline: 1.6455x; 1.6455x over previous
//
#include <hip/hip_runtime.h>
#include <math.h>

// PCEN: per-(b,k) IIR smoother over T + pointwise pow compression.
// x: [B=32, C=1, K=128, T=8000] fp32. One block per sequence (4096 blocks).
// R5: R4 minus the two regressions:
//  - regular cached float4 stores (R4's nontemporal stores defeated L2
//    write-combining of the 16B/lane @ 64B-stride pattern -> WRITE_SIZE
//    339MB vs 128MB ideal, 2.65x write amplification, dur 240us).
//  - no q[] prefix array: after the scan gives the entering value fin, the
//    apply phase REPLAYS g = fma(a,g,x_j) serially. Same op count as the
//    old a^j*fin+q_j form, but halves live VGPRs (no spill risk at CHUNK=16).
// Kept from R4: 512-thread blocks (4 blocks/CU for HBM/VALU phase
// staggering), g-space scan (g = f/s: recurrence is one fma, eps+f fuses
// as fma(s,g,eps)), raw v_exp_f32/v_log_f32 builtins.

constexpr int   T_LEN = 8000;
constexpr int   CHUNK = 16;
constexpr int   NTH   = 512;
constexpr int   NWAVE = NTH / 64;            // 8
constexpr int   NACT  = T_LEN / CHUNK;       // 500 active threads
constexpr int   KDIM  = 128;
constexpr float EPS_F = 1e-6f;
constexpr float LOG2E = 1.4426950408889634f;

typedef float f32x4 __attribute__((ext_vector_type(4)));

__global__ __launch_bounds__(NTH, 8) void pcen_kernel(
    const float* __restrict__ x,
    const float* __restrict__ log_s,
    const float* __restrict__ log_alpha,
    const float* __restrict__ log_delta,
    const float* __restrict__ log_r,
    float* __restrict__ out)
{
    __shared__ float wAs[NWAVE], wBs[NWAVE];

    const int seq  = blockIdx.x;              // seq = b*K + k  (C == 1)
    const int k    = seq & (KDIM - 1);
    const int tid  = threadIdx.x;
    const int lane = tid & 63;
    const int wave = tid >> 6;

    // Per-k parameters (uniform across the block). exp via hw v_exp_f32.
    const float ls      = log_s[k];
    const float e_ns    = __builtin_amdgcn_exp2f(-ls * LOG2E);   // e^{-ls}
    const float inv_s   = 1.0f + e_ns;                           // 1/s
    const float s       = 1.0f / inv_s;                          // sigmoid(ls)
    const float a       = e_ns * s;                              // 1 - s
    const float alpha   = __builtin_amdgcn_exp2f(log_alpha[k] * LOG2E);
    const float delta   = __builtin_amdgcn_exp2f(log_delta[k] * LOG2E);
    const float r       = __builtin_amdgcn_exp2f(log_r[k] * LOG2E);
    const float delta_r = __builtin_amdgcn_exp2f(r * log_delta[k] * LOG2E); // delta^r

    const float* xp = x   + (size_t)seq * T_LEN + tid * CHUNK;
    float*       op = out + (size_t)seq * T_LEN + tid * CHUNK;
    const bool active = tid < NACT;

    // ---- load 16 contiguous floats (four float4s), register-resident ----
    float xv[CHUNK];
    if (active) {
        #pragma unroll
        for (int v = 0; v < CHUNK / 4; ++v) {
            f32x4 t = ((const f32x4*)xp)[v];
            xv[4*v+0] = t[0]; xv[4*v+1] = t[1];
            xv[4*v+2] = t[2]; xv[4*v+3] = t[3];
        }
    }

    // ---- carry pass in g-space (g = f/s): g_t = a*g_{t-1} + x_t ----
    // Only the chunk-final value B is needed (prefixes are replayed later).
    // Thread 0 is the absolute start (A = 0 kills f_init dependence).
    float A = 1.0f, B = 0.0f;                 // identity for inactive tail
    if (active) {
        float g;
        if (tid == 0) {
            g = xv[0] * inv_s;                // f[0] = x[0]  ->  g[0] = x[0]/s
            #pragma unroll
            for (int j = 1; j < CHUNK; ++j) g = fmaf(a, g, xv[j]);
            A = 0.0f;
        } else {
            g = 0.0f;
            #pragma unroll
            for (int j = 0; j < CHUNK; ++j) g = fmaf(a, g, xv[j]);
            const float a2 = a * a, a4 = a2 * a2, a8 = a4 * a4;
            A = a8 * a8;                      // a^16
        }
        B = g;
    }

    // ---- intra-wave inclusive scan (64 lanes), compose current∘previous ----
    #pragma unroll
    for (int off = 1; off < 64; off <<= 1) {
        const float pA = __shfl_up(A, off, 64);
        const float pB = __shfl_up(B, off, 64);
        if (lane >= off) {
            B = fmaf(A, pB, B);
            A = A * pA;
        }
    }

    // ---- cross-wave: wave 0 scans the 8 wave carries, writes EXCLUSIVE prefixes ----
    if (lane == 63) { wAs[wave] = A; wBs[wave] = B; }
    __syncthreads();
    if (wave == 0) {
        float cA = (lane < NWAVE) ? wAs[lane] : 1.0f;
        float cB = (lane < NWAVE) ? wBs[lane] : 0.0f;
        #pragma unroll
        for (int off = 1; off < NWAVE; off <<= 1) {
            const float pA = __shfl_up(cA, off, 64);
            const float pB = __shfl_up(cB, off, 64);
            if (lane >= off) {
                cB = fmaf(cA, pB, cB);
                cA = cA * pA;
            }
        }
        if (lane < NWAVE - 1) { wAs[lane + 1] = cA; wBs[lane + 1] = cB; }
        if (lane == 0)        { wAs[0] = 1.0f;      wBs[0] = 0.0f;      }
    }
    __syncthreads();

    // entering g value for this thread (wave-prefix maps have A=0 past
    // thread 0, so entering value is just the composed B).
    float eA = __shfl_up(A, 1, 64);
    float eB = __shfl_up(B, 1, 64);
    if (lane == 0) { eA = 1.0f; eB = 0.0f; }
    float fin = fmaf(eA, wBs[wave], eB);

    // ---- apply: replay g_j = fma(a, g_{j-1}, x_j) from fin; PCEN; store ----
    if (active) {
        float g = fin;
        #pragma unroll
        for (int j = 0; j < CHUNK; ++j) {
            if (j == 0 && tid == 0) g = xv[0] * inv_s;   // absolute start
            else                    g = fmaf(a, g, xv[j]);
            const float lg  = __builtin_amdgcn_logf(fmaf(s, g, EPS_F));  // log2(eps+f)
            const float inv = __builtin_amdgcn_exp2f(-alpha * lg);       // (eps+f)^(-alpha)
            const float u   = fmaf(xv[j], inv, delta);
            xv[j] = __builtin_amdgcn_exp2f(r * __builtin_amdgcn_logf(u)) - delta_r;
        }
        #pragma unroll
        for (int v = 0; v < CHUNK / 4; ++v) {
            f32x4 t;
            t[0] = xv[4*v+0]; t[1] = xv[4*v+1];
            t[2] = xv[4*v+2]; t[3] = xv[4*v+3];
            ((f32x4*)op)[v] = t;
        }
    }
}

extern "C" void kernel_launch(void* const* d_in, const int* in_sizes, int n_in,
                              void* d_out, int out_size, void* d_ws, size_t ws_size,
                              hipStream_t stream) {
    const float* x         = (const float*)d_in[0];
    const float* log_s     = (const float*)d_in[1];
    const float* log_alpha = (const float*)d_in[2];
    const float* log_delta = (const float*)d_in[3];
    const float* log_r     = (const float*)d_in[4];
    float* out = (float*)d_out;

    const int nseq = in_sizes[0] / T_LEN;   // 32*1*128 = 4096 sequences
    pcen_kernel<<<nseq, NTH, 0, stream>>>(x, log_s, log_alpha, log_delta, log_r, out);
}